// Round 9
// baseline (97.089 us; speedup 1.0000x reference)
//
#include <hip/hip_runtime.h>
#include <math.h>

// Chamfer one-sided NN distance sum. N = M = 16384, D = 3, fp32 -> scalar fp32.
//
// MFMA formulation (R8, absmax 0.0 verified): d2(i,j) = |a|^2+|b|^2-2a.b via
// split-bf16 packing into one v_mfma_f32_32x32x16_bf16 per 32x32 tile.
//   A[i][k] = [ahx,ahy,ahz, ahx,ahy,ahz, alx,aly,alz, alx,aly,alz, a2h,a2l, 1,1]
//   B[j][k] = [-2bhx..,-2blx.., -2bhx..,-2blx.., 1,1, b2h,b2l]
// (bf16 products exact in fp32; split residual ~2^-18 -> absmax 0.0 measured)
//
// R9 change: 64 a-rows per block (2 row-tiles share each B fragment) ->
// B L2 traffic halves to 128 MB (~3.7 us); issue ~2.6 us; pair ~4-5 us.
// Totals are dominated by harness fixtures (~80 us of poison-fill/restore/
// gaps); this is the last controllable slice.
//
// k_prep: packs apack/bpack (512 KB each) into ws, zeroes out[0].
// k_pair: 256 blocks x 256 thr; 4 waves = 4 b-quarters (128 tiles each).
//   Per 2 tiles: 2 loads, 4 MFMA, 32 v_min3. Epilogue: LDS atomicMin over
//   64 rows (d2>=0 -> int-min on fp32 bits), sqrt, wave sum, one atomicAdd.
//   C/D layout (m74/m101, R8-verified): col=lane&31,
//   row=(reg&3)+8*(reg>>2)+4*(lane>>5).

#define NPTS 16384

typedef short s16x8 __attribute__((ext_vector_type(8)));
typedef float f32x16 __attribute__((ext_vector_type(16)));

__device__ __forceinline__ unsigned short f2bf(float x) {
    unsigned u = __float_as_uint(x);
    u = u + 0x7FFFu + ((u >> 16) & 1u);   // RNE
    return (unsigned short)(u >> 16);
}
__device__ __forceinline__ float bf2f(unsigned short h) {
    return __uint_as_float((unsigned)h << 16);
}

__global__ __launch_bounds__(256)
void cd_prep_kernel(const float* __restrict__ a, const float* __restrict__ b,
                    unsigned short* __restrict__ apack,
                    unsigned short* __restrict__ bpack,
                    float* __restrict__ out) {
    const int i = blockIdx.x * 256 + threadIdx.x;     // 0 .. 2*NPTS-1
    if (i == 0) out[0] = 0.0f;                        // pair kernel ordered after
    const bool isA = i < NPTS;
    const int p = isA ? i : i - NPTS;
    const float* src = isA ? a : b;
    const float x = src[3 * p + 0];
    const float y = src[3 * p + 1];
    const float z = src[3 * p + 2];
    const float n2 = fmaf(x, x, fmaf(y, y, z * z));

    const unsigned short hx = f2bf(x), hy = f2bf(y), hz = f2bf(z);
    const unsigned short lx = f2bf(x - bf2f(hx));
    const unsigned short ly = f2bf(y - bf2f(hy));
    const unsigned short lz = f2bf(z - bf2f(hz));
    const unsigned short n2h = f2bf(n2);
    const unsigned short n2l = f2bf(n2 - bf2f(n2h));
    const unsigned short one = f2bf(1.0f);

    if (isA) {
        unsigned short* o = apack + p * 16;
        o[0] = hx;  o[1] = hy;  o[2] = hz;  o[3] = hx;  o[4] = hy;  o[5] = hz;
        o[6] = lx;  o[7] = ly;  o[8] = lz;  o[9] = lx;  o[10] = ly; o[11] = lz;
        o[12] = n2h; o[13] = n2l; o[14] = one; o[15] = one;
    } else {
        const unsigned short thx = f2bf(-2.0f * bf2f(hx));
        const unsigned short thy = f2bf(-2.0f * bf2f(hy));
        const unsigned short thz = f2bf(-2.0f * bf2f(hz));
        const unsigned short tlx = f2bf(-2.0f * bf2f(lx));
        const unsigned short tly = f2bf(-2.0f * bf2f(ly));
        const unsigned short tlz = f2bf(-2.0f * bf2f(lz));
        unsigned short* o = bpack + p * 16;
        o[0] = thx; o[1] = thy; o[2] = thz; o[3] = tlx; o[4] = tly; o[5] = tlz;
        o[6] = thx; o[7] = thy; o[8] = thz; o[9] = tlx; o[10] = tly; o[11] = tlz;
        o[12] = one; o[13] = one; o[14] = n2h; o[15] = n2l;
    }
}

__global__ __launch_bounds__(256)
void cd_pair_kernel(const unsigned short* __restrict__ apack,
                    const unsigned short* __restrict__ bpack,
                    float* __restrict__ out) {
    __shared__ int rowmin[64];
    const int tid = threadIdx.x;
    if (tid < 64) rowmin[tid] = 0x7F800000;           // +inf bits
    __syncthreads();

    const int lane  = tid & 63;
    const int wave  = tid >> 6;                       // b-quarter 0..3
    const int col   = lane & 31;
    const int khalf = lane >> 5;                      // k in [8*khalf, 8*khalf+8)

    // Two A row-tiles per block: rows abase+col and abase+32+col
    const int abase = blockIdx.x * 64;
    const s16x8 af0 = *(const s16x8*)(apack + (size_t)(abase + col) * 16 + khalf * 8);
    const s16x8 af1 = *(const s16x8*)(apack + (size_t)(abase + 32 + col) * 16 + khalf * 8);

    // B fragment base for this wave's quarter (4096 b-points, 128 tiles)
    const unsigned short* bp =
        bpack + ((size_t)(wave * 4096 + col) * 16 + khalf * 8);

    f32x16 best0, best1, zero;
    #pragma unroll
    for (int r = 0; r < 16; ++r) {
        best0[r] = 3.4028235e38f; best1[r] = 3.4028235e38f; zero[r] = 0.0f;
    }

    #pragma unroll 4
    for (int t = 0; t < 128; t += 2) {                // 2 tiles per iteration
        const s16x8 b0 = *(const s16x8*)(bp + (size_t)t * 512);
        const s16x8 b1 = *(const s16x8*)(bp + (size_t)t * 512 + 512);
        const f32x16 c00 = __builtin_amdgcn_mfma_f32_32x32x16_bf16(af0, b0, zero, 0, 0, 0);
        const f32x16 c01 = __builtin_amdgcn_mfma_f32_32x32x16_bf16(af0, b1, zero, 0, 0, 0);
        const f32x16 c10 = __builtin_amdgcn_mfma_f32_32x32x16_bf16(af1, b0, zero, 0, 0, 0);
        const f32x16 c11 = __builtin_amdgcn_mfma_f32_32x32x16_bf16(af1, b1, zero, 0, 0, 0);
        #pragma unroll
        for (int r = 0; r < 16; ++r) {
            best0[r] = fminf(fminf(c00[r], c01[r]), best0[r]);  // v_min3_f32
            best1[r] = fminf(fminf(c10[r], c11[r]), best1[r]);
        }
    }

    // merge across waves/cols: d2 >= 0 -> int-min on fp32 bits
    #pragma unroll
    for (int r = 0; r < 16; ++r) {
        const int row = (r & 3) + 8 * (r >> 2) + 4 * khalf;
        atomicMin(&rowmin[row],      __float_as_int(best0[r]));
        atomicMin(&rowmin[32 + row], __float_as_int(best1[r]));
    }
    __syncthreads();

    if (tid < 64) {                                   // wave 0: 64 rows -> sum
        float d = sqrtf(fmaxf(__int_as_float(rowmin[tid]), 0.0f));
        for (int off = 32; off > 0; off >>= 1)
            d += __shfl_down(d, off, 64);
        if (tid == 0) atomicAdd(out, d);
    }
}

extern "C" void kernel_launch(void* const* d_in, const int* in_sizes, int n_in,
                              void* d_out, int out_size, void* d_ws, size_t ws_size,
                              hipStream_t stream) {
    const float* a = (const float*)d_in[0];
    const float* b = (const float*)d_in[1];
    float* out = (float*)d_out;
    unsigned short* apack = (unsigned short*)d_ws;          // NPTS*16 u16 = 512 KB
    unsigned short* bpack = apack + (size_t)NPTS * 16;      // + 512 KB

    cd_prep_kernel<<<(2 * NPTS) / 256, 256, 0, stream>>>(a, b, apack, bpack, out);
    cd_pair_kernel<<<NPTS / 64, 256, 0, stream>>>(apack, bpack, out);
}

// Round 10
// 77.386 us; speedup vs baseline: 1.2546x; 1.2546x over previous
//
#include <hip/hip_runtime.h>
#include <math.h>

// Chamfer one-sided NN distance sum. N = M = 16384, D = 3, fp32 -> scalar fp32.
//
// MFMA formulation (R8, absmax 0.0 verified): d2(i,j) = |a|^2+|b|^2-2a.b via
// split-bf16 packing, one v_mfma_f32_32x32x16_bf16 per 32x32 tile.
//
// R10: R9 was 80% idle (1 block/CU; LDS same-address atomicMin serialization,
// 2M conflict cycles). Fixes:
//  * operand swap: D[row=b][col=a] = mfma(bfrag, afrag, 0) -> min over b is
//    IN-LANE (16 regs = 16 b-rows of lane's a-col): fold to scalar at loop
//    end (15 v_min + 1 shfl_xor(32) to merge the khalf row-halves).
//  * grid (256 a-pairs x 8 b-slices) = 2048 blocks = 8/CU, ~20 waves/CU.
//    Wave: af0/af1 in regs, 16 b-tiles -> 32 MFMA + 256 v_min3.
//  * merge: tiny LDS atomicMin (256/block, 4-way) then 64 global atomicMin
//    per block into gmin[16384]; separate reduce kernel does sqrt+sum.
//
// k_prep: packs apack/bpack, inits gmin=+inf bits, zeroes out[0].
// k_pair: as above. C/D layout (R8-verified): col=lane&31,
//         row=(reg&3)+8*(reg>>2)+4*(lane>>5) — here row axis = b.
// k_red : d = sqrt(max(gmin,0)), wave butterfly + block sum, one atomicAdd.

#define NPTS 16384

typedef short s16x8 __attribute__((ext_vector_type(8)));
typedef float f32x16 __attribute__((ext_vector_type(16)));

__device__ __forceinline__ unsigned short f2bf(float x) {
    unsigned u = __float_as_uint(x);
    u = u + 0x7FFFu + ((u >> 16) & 1u);   // RNE
    return (unsigned short)(u >> 16);
}
__device__ __forceinline__ float bf2f(unsigned short h) {
    return __uint_as_float((unsigned)h << 16);
}

__global__ __launch_bounds__(256)
void cd_prep_kernel(const float* __restrict__ a, const float* __restrict__ b,
                    unsigned short* __restrict__ apack,
                    unsigned short* __restrict__ bpack,
                    int* __restrict__ gmin,
                    float* __restrict__ out) {
    const int i = blockIdx.x * 256 + threadIdx.x;     // 0 .. 2*NPTS-1
    if (i == 0) out[0] = 0.0f;
    if (i < NPTS) gmin[i] = 0x7F800000;               // +inf bits
    const bool isA = i < NPTS;
    const int p = isA ? i : i - NPTS;
    const float* src = isA ? a : b;
    const float x = src[3 * p + 0];
    const float y = src[3 * p + 1];
    const float z = src[3 * p + 2];
    const float n2 = fmaf(x, x, fmaf(y, y, z * z));

    const unsigned short hx = f2bf(x), hy = f2bf(y), hz = f2bf(z);
    const unsigned short lx = f2bf(x - bf2f(hx));
    const unsigned short ly = f2bf(y - bf2f(hy));
    const unsigned short lz = f2bf(z - bf2f(hz));
    const unsigned short n2h = f2bf(n2);
    const unsigned short n2l = f2bf(n2 - bf2f(n2h));
    const unsigned short one = f2bf(1.0f);

    if (isA) {
        unsigned short* o = apack + p * 16;
        o[0] = hx;  o[1] = hy;  o[2] = hz;  o[3] = hx;  o[4] = hy;  o[5] = hz;
        o[6] = lx;  o[7] = ly;  o[8] = lz;  o[9] = lx;  o[10] = ly; o[11] = lz;
        o[12] = n2h; o[13] = n2l; o[14] = one; o[15] = one;
    } else {
        const unsigned short thx = f2bf(-2.0f * bf2f(hx));
        const unsigned short thy = f2bf(-2.0f * bf2f(hy));
        const unsigned short thz = f2bf(-2.0f * bf2f(hz));
        const unsigned short tlx = f2bf(-2.0f * bf2f(lx));
        const unsigned short tly = f2bf(-2.0f * bf2f(ly));
        const unsigned short tlz = f2bf(-2.0f * bf2f(lz));
        unsigned short* o = bpack + p * 16;
        o[0] = thx; o[1] = thy; o[2] = thz; o[3] = tlx; o[4] = tly; o[5] = tlz;
        o[6] = thx; o[7] = thy; o[8] = thz; o[9] = tlx; o[10] = tly; o[11] = tlz;
        o[12] = one; o[13] = one; o[14] = n2h; o[15] = n2l;
    }
}

__global__ __launch_bounds__(256)
void cd_pair_kernel(const unsigned short* __restrict__ apack,
                    const unsigned short* __restrict__ bpack,
                    int* __restrict__ gmin) {
    __shared__ int smin[64];
    const int tid = threadIdx.x;
    if (tid < 64) smin[tid] = 0x7F800000;
    __syncthreads();

    const int lane  = tid & 63;
    const int wave  = tid >> 6;
    const int col   = lane & 31;
    const int khalf = lane >> 5;

    // Two a-tiles (64 a-points) fixed per block; lane's col = one a-point each
    const int abase = blockIdx.x * 64;
    const s16x8 af0 = *(const s16x8*)(apack + (size_t)(abase + col) * 16 + khalf * 8);
    const s16x8 af1 = *(const s16x8*)(apack + (size_t)(abase + 32 + col) * 16 + khalf * 8);

    // Wave's b-range: slice of 2048 pts, wave takes 512 pts = 16 tiles
    const unsigned short* bp = bpack +
        ((size_t)(blockIdx.y * 2048 + wave * 512 + col) * 16 + khalf * 8);

    f32x16 best0, best1, zero;
    #pragma unroll
    for (int r = 0; r < 16; ++r) {
        best0[r] = 3.4028235e38f; best1[r] = 3.4028235e38f; zero[r] = 0.0f;
    }

    #pragma unroll
    for (int t = 0; t < 16; t += 2) {                 // 2 b-tiles per iter
        const s16x8 b0 = *(const s16x8*)(bp + (size_t)t * 512);
        const s16x8 b1 = *(const s16x8*)(bp + (size_t)t * 512 + 512);
        // rows = b-points, cols = a-points
        const f32x16 c00 = __builtin_amdgcn_mfma_f32_32x32x16_bf16(b0, af0, zero, 0, 0, 0);
        const f32x16 c01 = __builtin_amdgcn_mfma_f32_32x32x16_bf16(b1, af0, zero, 0, 0, 0);
        const f32x16 c10 = __builtin_amdgcn_mfma_f32_32x32x16_bf16(b0, af1, zero, 0, 0, 0);
        const f32x16 c11 = __builtin_amdgcn_mfma_f32_32x32x16_bf16(b1, af1, zero, 0, 0, 0);
        #pragma unroll
        for (int r = 0; r < 16; ++r) {
            best0[r] = fminf(fminf(c00[r], c01[r]), best0[r]);  // v_min3_f32
            best1[r] = fminf(fminf(c10[r], c11[r]), best1[r]);
        }
    }

    // In-lane fold over 16 regs (16 b-rows), then merge khalf halves (the
    // other 16 rows of the same a-col live in lane^32).
    float m0 = best0[0], m1 = best1[0];
    #pragma unroll
    for (int r = 1; r < 16; ++r) {
        m0 = fminf(m0, best0[r]);
        m1 = fminf(m1, best1[r]);
    }
    m0 = fminf(m0, __shfl_xor(m0, 32, 64));
    m1 = fminf(m1, __shfl_xor(m1, 32, 64));

    if (lane < 32) {                                  // 4-way LDS contention only
        atomicMin(&smin[col],      __float_as_int(m0));
        atomicMin(&smin[32 + col], __float_as_int(m1));
    }
    __syncthreads();
    if (tid < 64)                                     // 8 contenders per address
        atomicMin(&gmin[abase + tid], smin[tid]);
}

__global__ __launch_bounds__(256)
void cd_reduce_kernel(const int* __restrict__ gmin, float* __restrict__ out) {
    __shared__ float red[4];
    const int i = blockIdx.x * 256 + threadIdx.x;
    float d = sqrtf(fmaxf(__int_as_float(gmin[i]), 0.0f));

    for (int off = 32; off > 0; off >>= 1)
        d += __shfl_down(d, off, 64);

    const int lane = threadIdx.x & 63;
    const int wave = threadIdx.x >> 6;
    if (lane == 0) red[wave] = d;
    __syncthreads();
    if (threadIdx.x == 0)
        atomicAdd(out, red[0] + red[1] + red[2] + red[3]);
}

extern "C" void kernel_launch(void* const* d_in, const int* in_sizes, int n_in,
                              void* d_out, int out_size, void* d_ws, size_t ws_size,
                              hipStream_t stream) {
    const float* a = (const float*)d_in[0];
    const float* b = (const float*)d_in[1];
    float* out = (float*)d_out;
    unsigned short* apack = (unsigned short*)d_ws;          // 512 KB
    unsigned short* bpack = apack + (size_t)NPTS * 16;      // 512 KB
    int* gmin = (int*)(bpack + (size_t)NPTS * 16);          // 64 KB

    cd_prep_kernel<<<(2 * NPTS) / 256, 256, 0, stream>>>(a, b, apack, bpack, gmin, out);

    dim3 grid(NPTS / 64, 8);                                // 256 x 8 = 2048 blocks
    cd_pair_kernel<<<grid, 256, 0, stream>>>(apack, bpack, gmin);

    cd_reduce_kernel<<<NPTS / 256, 256, 0, stream>>>(gmin, out);
}